// Round 2
// baseline (866.446 us; speedup 1.0000x reference)
//
#include <hip/hip_runtime.h>

#define EPS 1e-7f
#define CCH 42
#define NCON 8

// ---------------------------------------------------------------------------
// Kernel 1: tau_total reduction + transmission exps.
// Each thread handles TWO consecutive (n,c) pairs: 64 B contiguous tau load,
// float2 coalesced stores.
// ---------------------------------------------------------------------------
__global__ __launch_bounds__(256) void k_trans(
    const float* __restrict__ tau,
    const float* __restrict__ mu_direct,
    const float* __restrict__ mu_diffuse,
    float* __restrict__ out, int npairs, size_t nctot)
{
    int p = blockIdx.x * 256 + threadIdx.x;
    if (p >= npairs) return;
    int i0 = 2 * p;
    int i1 = i0 + 1;
    const float4* t4 = (const float4*)tau + (size_t)p * 4;
    float4 a = t4[0], b = t4[1], c = t4[2], d = t4[3];
    float s0 = ((a.x + a.y) + (a.z + a.w)) + ((b.x + b.y) + (b.z + b.w));
    float s1 = ((c.x + c.y) + (c.z + c.w)) + ((d.x + d.y) + (d.z + d.w));
    int n0 = i0 / CCH;
    int n1 = i1 / CCH;
    float md0 = mu_direct[n0] + EPS, md1 = mu_direct[n1] + EPS;
    float mf0 = mu_diffuse[n0] + EPS, mf1 = mu_diffuse[n1] + EPS;
    float2 td = make_float2(__expf(__fdividef(-s0, md0)), __expf(__fdividef(-s1, md1)));
    float2 tf = make_float2(__expf(__fdividef(-s0, mf0)), __expf(__fdividef(-s1, mf1)));
    *(float2*)(out + i0) = td;
    *(float2*)(out + nctot + i0) = tf;
}

// ---------------------------------------------------------------------------
// Per-channel MLP (dims NIN -> 5 -> 4 -> 4 -> 3) + 3-way softmax.
// `c` is wave-uniform, so all weight/bias loads compile to s_load and the
// FMAs take their weight operand straight from SGPRs.
// ---------------------------------------------------------------------------
template<int NIN>
__device__ __forceinline__ void mlp_softmax3(
    const float x[NIN], int c,
    const float* __restrict__ W0, const float* __restrict__ b0,
    const float* __restrict__ W1, const float* __restrict__ b1,
    const float* __restrict__ W2, const float* __restrict__ b2,
    const float* __restrict__ W3, const float* __restrict__ b3,
    float o[3])
{
    float h0[5];
#pragma unroll
    for (int j = 0; j < 5; ++j) {
        const float* w = W0 + (c * 5 + j) * NIN;
        float a = b0[c * 5 + j];
#pragma unroll
        for (int i = 0; i < NIN; ++i) a = fmaf(x[i], w[i], a);
        h0[j] = fmaxf(a, 0.0f);
    }
    float h1[4];
#pragma unroll
    for (int j = 0; j < 4; ++j) {
        const float* w = W1 + (c * 4 + j) * 5;
        float a = b1[c * 4 + j];
#pragma unroll
        for (int i = 0; i < 5; ++i) a = fmaf(h0[i], w[i], a);
        h1[j] = fmaxf(a, 0.0f);
    }
    float h2[4];
#pragma unroll
    for (int j = 0; j < 4; ++j) {
        const float* w = W2 + (c * 4 + j) * 4;
        float a = b2[c * 4 + j];
#pragma unroll
        for (int i = 0; i < 4; ++i) a = fmaf(h1[i], w[i], a);
        h2[j] = fmaxf(a, 0.0f);
    }
    float lg[3];
#pragma unroll
    for (int j = 0; j < 3; ++j) {
        const float* w = W3 + (c * 3 + j) * 4;
        float a = b3[c * 3 + j];
#pragma unroll
        for (int i = 0; i < 4; ++i) a = fmaf(h2[i], w[i], a);
        lg[j] = a;
    }
    float m = fmaxf(fmaxf(lg[0], lg[1]), lg[2]);
    float e0 = __expf(lg[0] - m);
    float e1 = __expf(lg[1] - m);
    float e2 = __expf(lg[2] - m);
    float r = __fdividef(1.0f, e0 + e1 + e2);
    o[0] = e0 * r;
    o[1] = e1 * r;
    o[2] = e2 * r;
}

// ---------------------------------------------------------------------------
// Kernel 2: per-channel MLP softmax splits. No LDS.
// Global wave G: sample group n0 = (G/6)*64 (lane = sample), channel group
// g = G%6 -> channels 7g..7g+6. Direct scattered 12 B stores per channel;
// the wave's overall output region is contiguous, L2 merges.
// ---------------------------------------------------------------------------
__global__ __launch_bounds__(256) void k_mlp(
    const float* __restrict__ cons,
    const float* __restrict__ mu_direct,
    const float* __restrict__ Wd0, const float* __restrict__ bd0,
    const float* __restrict__ Wf0, const float* __restrict__ bf0,
    const float* __restrict__ Wd1, const float* __restrict__ bd1,
    const float* __restrict__ Wf1, const float* __restrict__ bf1,
    const float* __restrict__ Wd2, const float* __restrict__ bd2,
    const float* __restrict__ Wf2, const float* __restrict__ bf2,
    const float* __restrict__ Wd3, const float* __restrict__ bd3,
    const float* __restrict__ Wf3, const float* __restrict__ bf3,
    float* __restrict__ out, int N)
{
    const int lane = threadIdx.x & 63;
    int G = __builtin_amdgcn_readfirstlane(blockIdx.x * 4 + (threadIdx.x >> 6));
    int g  = G % 6;
    int n0 = (G / 6) * 64;
    int n  = n0 + lane;

    float4 c0 = *(const float4*)(cons + (size_t)n * NCON);
    float4 c1 = *(const float4*)(cons + (size_t)n * NCON + 4);
    float mu  = mu_direct[n];
    float inv = __fdividef(1.0f, mu + EPS);
    float xf[8] = {c0.x, c0.y, c0.z, c0.w, c1.x, c1.y, c1.z, c1.w};
    float xd[9];
#pragma unroll
    for (int i = 0; i < 8; ++i) xd[i] = xf[i] * inv;
    xd[8] = mu;

    size_t nctot = (size_t)N * CCH;
    float* based = out + 2 * nctot + (size_t)n * (CCH * 3);
    float* basef = out + 5 * nctot + (size_t)n * (CCH * 3);

#pragma unroll 1
    for (int ci = 0; ci < 7; ++ci) {
        int c = 7 * g + ci;   // wave-uniform
        float od[3], og[3];
        mlp_softmax3<9>(xd, c, Wd0, bd0, Wd1, bd1, Wd2, bd2, Wd3, bd3, od);
        mlp_softmax3<8>(xf, c, Wf0, bf0, Wf1, bf1, Wf2, bf2, Wf3, bf3, og);
        float* pd = based + c * 3;
        float* pf = basef + c * 3;
        *(float2*)pd = make_float2(od[0], od[1]);
        pd[2] = od[2];
        *(float2*)pf = make_float2(og[0], og[1]);
        pf[2] = og[2];
    }
}

extern "C" void kernel_launch(void* const* d_in, const int* in_sizes, int n_in,
                              void* d_out, int out_size, void* d_ws, size_t ws_size,
                              hipStream_t stream) {
    const float* tau  = (const float*)d_in[0];
    const float* mud  = (const float*)d_in[1];
    const float* muf  = (const float*)d_in[2];
    const float* cons = (const float*)d_in[3];
    // setup_inputs() dict order: Wd{i}, bd{i}, Wf{i}, bf{i} interleaved per layer.
    const float* Wd0 = (const float*)d_in[4];  const float* bd0 = (const float*)d_in[5];
    const float* Wf0 = (const float*)d_in[6];  const float* bf0 = (const float*)d_in[7];
    const float* Wd1 = (const float*)d_in[8];  const float* bd1 = (const float*)d_in[9];
    const float* Wf1 = (const float*)d_in[10]; const float* bf1 = (const float*)d_in[11];
    const float* Wd2 = (const float*)d_in[12]; const float* bd2 = (const float*)d_in[13];
    const float* Wf2 = (const float*)d_in[14]; const float* bf2 = (const float*)d_in[15];
    const float* Wd3 = (const float*)d_in[16]; const float* bd3 = (const float*)d_in[17];
    const float* Wf3 = (const float*)d_in[18]; const float* bf3 = (const float*)d_in[19];
    float* out = (float*)d_out;

    int N = in_sizes[1];            // mu_direct element count = N
    size_t nctot = (size_t)N * CCH; // N*C
    int npairs = (int)(nctot / 2);
    k_trans<<<(npairs + 255) / 256, 256, 0, stream>>>(tau, mud, muf, out, npairs, nctot);

    int nwaves = (N / 64) * 6;
    k_mlp<<<nwaves / 4, 256, 0, stream>>>(cons, mud,
                                          Wd0, bd0, Wf0, bf0,
                                          Wd1, bd1, Wf1, bf1,
                                          Wd2, bd2, Wf2, bf2,
                                          Wd3, bd3, Wf3, bf3,
                                          out, N);
}

// Round 3
// 407.293 us; speedup vs baseline: 2.1273x; 2.1273x over previous
//
#include <hip/hip_runtime.h>

#define EPS 1e-7f
#define CCH 42
#define NCON 8

// ---------------------------------------------------------------------------
// Kernel 1: tau_total reduction + transmission exps.
// Thread i <-> (n,c); tau[n,c,:] = tau[8i..8i+7]. Coalesced float4 reads,
// coalesced b32 stores. Fast divide (rcp+mul) instead of full-precision div.
// ---------------------------------------------------------------------------
__global__ __launch_bounds__(256) void k_trans(
    const float* __restrict__ tau,
    const float* __restrict__ mu_direct,
    const float* __restrict__ mu_diffuse,
    float* __restrict__ out, int total, size_t nctot)
{
    int i = blockIdx.x * 256 + threadIdx.x;
    if (i >= total) return;
    const float4* t4 = (const float4*)tau + (size_t)i * 2;
    float4 a = t4[0];
    float4 b = t4[1];
    float s = ((a.x + a.y) + (a.z + a.w)) + ((b.x + b.y) + (b.z + b.w));
    int n = i / CCH;
    float md = mu_direct[n] + EPS;
    float mf = mu_diffuse[n] + EPS;
    out[i] = __expf(__fdividef(-s, md));
    out[nctot + i] = __expf(__fdividef(-s, mf));
}

// ---------------------------------------------------------------------------
// Per-channel MLP (dims NIN -> 5 -> 4 -> 4 -> 3) + 3-way softmax.
// `c` is wave-uniform, so weight/bias loads compile to s_load and FMAs take
// the weight operand from SGPRs.
// ---------------------------------------------------------------------------
template<int NIN>
__device__ __forceinline__ void mlp_softmax3(
    const float x[NIN], int c,
    const float* __restrict__ W0, const float* __restrict__ b0,
    const float* __restrict__ W1, const float* __restrict__ b1,
    const float* __restrict__ W2, const float* __restrict__ b2,
    const float* __restrict__ W3, const float* __restrict__ b3,
    float o[3])
{
    float h0[5];
#pragma unroll
    for (int j = 0; j < 5; ++j) {
        const float* w = W0 + (c * 5 + j) * NIN;
        float a = b0[c * 5 + j];
#pragma unroll
        for (int i = 0; i < NIN; ++i) a = fmaf(x[i], w[i], a);
        h0[j] = fmaxf(a, 0.0f);
    }
    float h1[4];
#pragma unroll
    for (int j = 0; j < 4; ++j) {
        const float* w = W1 + (c * 4 + j) * 5;
        float a = b1[c * 4 + j];
#pragma unroll
        for (int i = 0; i < 5; ++i) a = fmaf(h0[i], w[i], a);
        h1[j] = fmaxf(a, 0.0f);
    }
    float h2[4];
#pragma unroll
    for (int j = 0; j < 4; ++j) {
        const float* w = W2 + (c * 4 + j) * 4;
        float a = b2[c * 4 + j];
#pragma unroll
        for (int i = 0; i < 4; ++i) a = fmaf(h1[i], w[i], a);
        h2[j] = fmaxf(a, 0.0f);
    }
    float lg[3];
#pragma unroll
    for (int j = 0; j < 3; ++j) {
        const float* w = W3 + (c * 3 + j) * 4;
        float a = b3[c * 3 + j];
#pragma unroll
        for (int i = 0; i < 4; ++i) a = fmaf(h2[i], w[i], a);
        lg[j] = a;
    }
    float m = fmaxf(fmaxf(lg[0], lg[1]), lg[2]);
    float e0 = __expf(lg[0] - m);
    float e1 = __expf(lg[1] - m);
    float e2 = __expf(lg[2] - m);
    float r = __fdividef(1.0f, e0 + e1 + e2);
    o[0] = e0 * r;
    o[1] = e1 * r;
    o[2] = e2 * r;
}

// ---------------------------------------------------------------------------
// Kernel 2: per-channel MLP softmax splits.
// gridDim.y = 2: y==0 -> e_split_direct, y==1 -> e_split_diffuse.
// Block = 384 threads = 6 waves, 64 samples; wave w computes channels
// 7w..7w+6 for its 64 lanes (lane = sample). ONE 64x127 f32 LDS tile
// (32.3 KB -> ~4 blocks/CU). Stride 127 == -1 mod 32: staging writes are
// 2-way bank aliased = free. Then block-cooperative contiguous float2
// writeout of the 64x126 tile (full 64 B sectors, no write amplification).
// ---------------------------------------------------------------------------
__global__ __launch_bounds__(384) void k_mlp(
    const float* __restrict__ cons,
    const float* __restrict__ mu_direct,
    const float* __restrict__ Wd0, const float* __restrict__ bd0,
    const float* __restrict__ Wf0, const float* __restrict__ bf0,
    const float* __restrict__ Wd1, const float* __restrict__ bd1,
    const float* __restrict__ Wf1, const float* __restrict__ bf1,
    const float* __restrict__ Wd2, const float* __restrict__ bd2,
    const float* __restrict__ Wf2, const float* __restrict__ bf2,
    const float* __restrict__ Wd3, const float* __restrict__ bd3,
    const float* __restrict__ Wf3, const float* __restrict__ bf3,
    float* __restrict__ out, int N)
{
    __shared__ float es[64 * 127];
    const int tid  = threadIdx.x;
    const int lane = tid & 63;
    const int wave = tid >> 6;
    const int n0   = blockIdx.x * 64;
    const int n    = n0 + lane;
    const bool direct = (blockIdx.y == 0);

    float4 c0 = *(const float4*)(cons + (size_t)n * NCON);
    float4 c1 = *(const float4*)(cons + (size_t)n * NCON + 4);
    float x[9] = {c0.x, c0.y, c0.z, c0.w, c1.x, c1.y, c1.z, c1.w, 0.0f};
    if (direct) {
        float mu  = mu_direct[n];
        float inv = __fdividef(1.0f, mu + EPS);
#pragma unroll
        for (int i = 0; i < 8; ++i) x[i] *= inv;
        x[8] = mu;
#pragma unroll 1
        for (int ci = 0; ci < 7; ++ci) {
            int c = __builtin_amdgcn_readfirstlane(wave * 7 + ci);
            float o[3];
            mlp_softmax3<9>(x, c, Wd0, bd0, Wd1, bd1, Wd2, bd2, Wd3, bd3, o);
#pragma unroll
            for (int k = 0; k < 3; ++k) es[lane * 127 + c * 3 + k] = o[k];
        }
    } else {
#pragma unroll 1
        for (int ci = 0; ci < 7; ++ci) {
            int c = __builtin_amdgcn_readfirstlane(wave * 7 + ci);
            float o[3];
            mlp_softmax3<8>(x, c, Wf0, bf0, Wf1, bf1, Wf2, bf2, Wf3, bf3, o);
#pragma unroll
            for (int k = 0; k < 3; ++k) es[lane * 127 + c * 3 + k] = o[k];
        }
    }
    __syncthreads();

    size_t nctot = (size_t)N * CCH;
    float* base = out + (direct ? 2 : 5) * nctot + (size_t)n0 * (CCH * 3);
    // 64 rows x 126 floats = 64*63 float2, contiguous in global.
    for (int idx = tid; idx < 64 * 63; idx += 384) {
        int r = idx / 63;
        int q = idx - r * 63;
        float2 v;
        v.x = es[r * 127 + 2 * q];
        v.y = es[r * 127 + 2 * q + 1];
        ((float2*)base)[idx] = v;
    }
}

extern "C" void kernel_launch(void* const* d_in, const int* in_sizes, int n_in,
                              void* d_out, int out_size, void* d_ws, size_t ws_size,
                              hipStream_t stream) {
    const float* tau  = (const float*)d_in[0];
    const float* mud  = (const float*)d_in[1];
    const float* muf  = (const float*)d_in[2];
    const float* cons = (const float*)d_in[3];
    // setup_inputs() dict order: Wd{i}, bd{i}, Wf{i}, bf{i} interleaved per layer.
    const float* Wd0 = (const float*)d_in[4];  const float* bd0 = (const float*)d_in[5];
    const float* Wf0 = (const float*)d_in[6];  const float* bf0 = (const float*)d_in[7];
    const float* Wd1 = (const float*)d_in[8];  const float* bd1 = (const float*)d_in[9];
    const float* Wf1 = (const float*)d_in[10]; const float* bf1 = (const float*)d_in[11];
    const float* Wd2 = (const float*)d_in[12]; const float* bd2 = (const float*)d_in[13];
    const float* Wf2 = (const float*)d_in[14]; const float* bf2 = (const float*)d_in[15];
    const float* Wd3 = (const float*)d_in[16]; const float* bd3 = (const float*)d_in[17];
    const float* Wf3 = (const float*)d_in[18]; const float* bf3 = (const float*)d_in[19];
    float* out = (float*)d_out;

    int N = in_sizes[1];            // mu_direct element count = N
    int total = N * CCH;
    k_trans<<<(total + 255) / 256, 256, 0, stream>>>(tau, mud, muf, out, total, (size_t)total);

    dim3 grid(N / 64, 2);
    k_mlp<<<grid, 384, 0, stream>>>(cons, mud,
                                    Wd0, bd0, Wf0, bf0,
                                    Wd1, bd1, Wf1, bf1,
                                    Wd2, bd2, Wf2, bf2,
                                    Wd3, bd3, Wf3, bf3,
                                    out, N);
}

// Round 4
// 307.851 us; speedup vs baseline: 2.8145x; 1.3230x over previous
//
#include <hip/hip_runtime.h>

#define EPS 1e-7f
#define CCH 42
#define NCON 8

// ---------------------------------------------------------------------------
// Per-channel MLP (dims NIN -> 5 -> 4 -> 4 -> 3) + 3-way softmax.
// `c` is wave-uniform, so weight/bias loads compile to s_load and FMAs take
// the weight operand from SGPRs.
// ---------------------------------------------------------------------------
template<int NIN>
__device__ __forceinline__ void mlp_softmax3(
    const float x[NIN], int c,
    const float* __restrict__ W0, const float* __restrict__ b0,
    const float* __restrict__ W1, const float* __restrict__ b1,
    const float* __restrict__ W2, const float* __restrict__ b2,
    const float* __restrict__ W3, const float* __restrict__ b3,
    float o[3])
{
    float h0[5];
#pragma unroll
    for (int j = 0; j < 5; ++j) {
        const float* w = W0 + (c * 5 + j) * NIN;
        float a = b0[c * 5 + j];
#pragma unroll
        for (int i = 0; i < NIN; ++i) a = fmaf(x[i], w[i], a);
        h0[j] = fmaxf(a, 0.0f);
    }
    float h1[4];
#pragma unroll
    for (int j = 0; j < 4; ++j) {
        const float* w = W1 + (c * 4 + j) * 5;
        float a = b1[c * 4 + j];
#pragma unroll
        for (int i = 0; i < 5; ++i) a = fmaf(h0[i], w[i], a);
        h1[j] = fmaxf(a, 0.0f);
    }
    float h2[4];
#pragma unroll
    for (int j = 0; j < 4; ++j) {
        const float* w = W2 + (c * 4 + j) * 4;
        float a = b2[c * 4 + j];
#pragma unroll
        for (int i = 0; i < 4; ++i) a = fmaf(h1[i], w[i], a);
        h2[j] = fmaxf(a, 0.0f);
    }
    float lg[3];
#pragma unroll
    for (int j = 0; j < 3; ++j) {
        const float* w = W3 + (c * 3 + j) * 4;
        float a = b3[c * 3 + j];
#pragma unroll
        for (int i = 0; i < 4; ++i) a = fmaf(h2[i], w[i], a);
        lg[j] = a;
    }
    float m = fmaxf(fmaxf(lg[0], lg[1]), lg[2]);
    float e0 = __expf(lg[0] - m);
    float e1 = __expf(lg[1] - m);
    float e2 = __expf(lg[2] - m);
    float r = __fdividef(1.0f, e0 + e1 + e2);
    o[0] = e0 * r;
    o[1] = e1 * r;
    o[2] = e2 * r;
}

// ---------------------------------------------------------------------------
// Fused kernel. grid = (N/64, 2). Block = 384 threads (6 waves), 64 samples.
//   Phase A: MLP softmax splits for one output (y=0 direct, y=1 diffuse)
//            -> 64x127 f32 LDS tile (32.3 KB, 4 blocks/CU).
//            Wave w computes channels 7w..7w+6, lane = sample.
//   Phase B: block-cooperative contiguous float2 writeout (full sectors).
//   Phase C: a disjoint 1344-element chunk of the tau reduction + both
//            transmission exps. Memory-bound; overlaps other resident
//            blocks' phase A (blocks are staggered), so HBM stays fed
//            while MLP chains stall and vice versa.
// ---------------------------------------------------------------------------
__global__ __launch_bounds__(384, 6) void k_fused(
    const float* __restrict__ tau,
    const float* __restrict__ mu_direct,
    const float* __restrict__ mu_diffuse,
    const float* __restrict__ cons,
    const float* __restrict__ Wd0, const float* __restrict__ bd0,
    const float* __restrict__ Wf0, const float* __restrict__ bf0,
    const float* __restrict__ Wd1, const float* __restrict__ bd1,
    const float* __restrict__ Wf1, const float* __restrict__ bf1,
    const float* __restrict__ Wd2, const float* __restrict__ bd2,
    const float* __restrict__ Wf2, const float* __restrict__ bf2,
    const float* __restrict__ Wd3, const float* __restrict__ bd3,
    const float* __restrict__ Wf3, const float* __restrict__ bf3,
    float* __restrict__ out, int N)
{
    __shared__ float es[64 * 127];
    const int tid  = threadIdx.x;
    const int lane = tid & 63;
    const int wave = tid >> 6;
    const int n0   = blockIdx.x * 64;
    const int n    = n0 + lane;
    const bool direct = (blockIdx.y == 0);
    const size_t nctot = (size_t)N * CCH;

    // ---- Phase A: MLP -> LDS ----
    float4 c0 = *(const float4*)(cons + (size_t)n * NCON);
    float4 c1 = *(const float4*)(cons + (size_t)n * NCON + 4);
    float x[9] = {c0.x, c0.y, c0.z, c0.w, c1.x, c1.y, c1.z, c1.w, 0.0f};
    if (direct) {
        float mu  = mu_direct[n];
        float inv = __fdividef(1.0f, mu + EPS);
#pragma unroll
        for (int i = 0; i < 8; ++i) x[i] *= inv;
        x[8] = mu;
#pragma unroll 1
        for (int ci = 0; ci < 7; ++ci) {
            int c = __builtin_amdgcn_readfirstlane(wave * 7 + ci);
            float o[3];
            mlp_softmax3<9>(x, c, Wd0, bd0, Wd1, bd1, Wd2, bd2, Wd3, bd3, o);
#pragma unroll
            for (int k = 0; k < 3; ++k) es[lane * 127 + c * 3 + k] = o[k];
        }
    } else {
#pragma unroll 1
        for (int ci = 0; ci < 7; ++ci) {
            int c = __builtin_amdgcn_readfirstlane(wave * 7 + ci);
            float o[3];
            mlp_softmax3<8>(x, c, Wf0, bf0, Wf1, bf1, Wf2, bf2, Wf3, bf3, o);
#pragma unroll
            for (int k = 0; k < 3; ++k) es[lane * 127 + c * 3 + k] = o[k];
        }
    }
    __syncthreads();

    // ---- Phase B: coalesced writeout of the 64x126 tile ----
    float* base = out + (direct ? 2 : 5) * nctot + (size_t)n0 * (CCH * 3);
    for (int idx = tid; idx < 64 * 63; idx += 384) {
        int r = idx / 63;
        int q = idx - r * 63;
        float2 v;
        v.x = es[r * 127 + 2 * q];
        v.y = es[r * 127 + 2 * q + 1];
        ((float2*)base)[idx] = v;
    }

    // ---- Phase C: tau reduction + transmission exps, disjoint chunk ----
    // chunk id over all (x,y) blocks; NC elements split exactly.
    const int nblk = gridDim.x * 2;
    const int cid  = blockIdx.y * gridDim.x + blockIdx.x;
    const int per  = (int)(nctot / nblk);        // 1344 for N=524288
    const int base_e = cid * per;
#pragma unroll
    for (int it = 0; it < 4; ++it) {
        int off = it * 384 + tid;
        if (off < per) {
            int e = base_e + off;
            const float4* t4 = (const float4*)tau + (size_t)e * 2;
            float4 a = t4[0];
            float4 b = t4[1];
            float s = ((a.x + a.y) + (a.z + a.w)) + ((b.x + b.y) + (b.z + b.w));
            int nn = e / CCH;
            float md = mu_direct[nn] + EPS;
            float mf = mu_diffuse[nn] + EPS;
            out[e] = __expf(__fdividef(-s, md));
            out[nctot + e] = __expf(__fdividef(-s, mf));
        }
    }
}

extern "C" void kernel_launch(void* const* d_in, const int* in_sizes, int n_in,
                              void* d_out, int out_size, void* d_ws, size_t ws_size,
                              hipStream_t stream) {
    const float* tau  = (const float*)d_in[0];
    const float* mud  = (const float*)d_in[1];
    const float* muf  = (const float*)d_in[2];
    const float* cons = (const float*)d_in[3];
    // setup_inputs() dict order: Wd{i}, bd{i}, Wf{i}, bf{i} interleaved per layer.
    const float* Wd0 = (const float*)d_in[4];  const float* bd0 = (const float*)d_in[5];
    const float* Wf0 = (const float*)d_in[6];  const float* bf0 = (const float*)d_in[7];
    const float* Wd1 = (const float*)d_in[8];  const float* bd1 = (const float*)d_in[9];
    const float* Wf1 = (const float*)d_in[10]; const float* bf1 = (const float*)d_in[11];
    const float* Wd2 = (const float*)d_in[12]; const float* bd2 = (const float*)d_in[13];
    const float* Wf2 = (const float*)d_in[14]; const float* bf2 = (const float*)d_in[15];
    const float* Wd3 = (const float*)d_in[16]; const float* bd3 = (const float*)d_in[17];
    const float* Wf3 = (const float*)d_in[18]; const float* bf3 = (const float*)d_in[19];
    float* out = (float*)d_out;

    int N = in_sizes[1];            // mu_direct element count = N
    dim3 grid(N / 64, 2);
    k_fused<<<grid, 384, 0, stream>>>(tau, mud, muf, cons,
                                      Wd0, bd0, Wf0, bf0,
                                      Wd1, bd1, Wf1, bf1,
                                      Wd2, bd2, Wf2, bf2,
                                      Wd3, bd3, Wf3, bf3,
                                      out, N);
}

// Round 6
// 301.527 us; speedup vs baseline: 2.8735x; 1.0210x over previous
//
#include <hip/hip_runtime.h>

#define EPS 1e-7f
#define CCH 42
#define NCON 8

typedef float v4f __attribute__((ext_vector_type(4)));
typedef float v2f __attribute__((ext_vector_type(2)));

// ---------------------------------------------------------------------------
// Per-channel MLP (dims NIN -> 5 -> 4 -> 4 -> 3) + 3-way softmax.
// `c` is wave-uniform, so weight/bias loads compile to s_load and FMAs take
// the weight operand from SGPRs.
// ---------------------------------------------------------------------------
template<int NIN>
__device__ __forceinline__ void mlp_softmax3(
    const float x[NIN], int c,
    const float* __restrict__ W0, const float* __restrict__ b0,
    const float* __restrict__ W1, const float* __restrict__ b1,
    const float* __restrict__ W2, const float* __restrict__ b2,
    const float* __restrict__ W3, const float* __restrict__ b3,
    float o[3])
{
    float h0[5];
#pragma unroll
    for (int j = 0; j < 5; ++j) {
        const float* w = W0 + (c * 5 + j) * NIN;
        float a = b0[c * 5 + j];
#pragma unroll
        for (int i = 0; i < NIN; ++i) a = fmaf(x[i], w[i], a);
        h0[j] = fmaxf(a, 0.0f);
    }
    float h1[4];
#pragma unroll
    for (int j = 0; j < 4; ++j) {
        const float* w = W1 + (c * 4 + j) * 5;
        float a = b1[c * 4 + j];
#pragma unroll
        for (int i = 0; i < 5; ++i) a = fmaf(h0[i], w[i], a);
        h1[j] = fmaxf(a, 0.0f);
    }
    float h2[4];
#pragma unroll
    for (int j = 0; j < 4; ++j) {
        const float* w = W2 + (c * 4 + j) * 4;
        float a = b2[c * 4 + j];
#pragma unroll
        for (int i = 0; i < 4; ++i) a = fmaf(h1[i], w[i], a);
        h2[j] = fmaxf(a, 0.0f);
    }
    float lg[3];
#pragma unroll
    for (int j = 0; j < 3; ++j) {
        const float* w = W3 + (c * 3 + j) * 4;
        float a = b3[c * 3 + j];
#pragma unroll
        for (int i = 0; i < 4; ++i) a = fmaf(h2[i], w[i], a);
        lg[j] = a;
    }
    float m = fmaxf(fmaxf(lg[0], lg[1]), lg[2]);
    float e0 = __expf(lg[0] - m);
    float e1 = __expf(lg[1] - m);
    float e2 = __expf(lg[2] - m);
    float r = __fdividef(1.0f, e0 + e1 + e2);
    o[0] = e0 * r;
    o[1] = e1 * r;
    o[2] = e2 * r;
}

// ---------------------------------------------------------------------------
// Fused kernel, software-pipelined. grid = (N/64, 2). Block = 384 thr / 6 waves.
//   Phase 0: ISSUE the block's tau-chunk loads (7 nt v4f per thread) -- HBM
//            latency hides under phase A's ~2800-cycle VALU chain (T14).
//   Phase A: MLP softmax splits (y=0 direct, y=1 diffuse) -> 64x127 LDS tile.
//   Phase B: block-cooperative contiguous nt v2f writeout (full sectors).
//   Phase C: consume prefetched tau regs: sum -> exp -> nt stores.
// ---------------------------------------------------------------------------
__global__ __launch_bounds__(384, 6) void k_fused(
    const float* __restrict__ tau,
    const float* __restrict__ mu_direct,
    const float* __restrict__ mu_diffuse,
    const float* __restrict__ cons,
    const float* __restrict__ Wd0, const float* __restrict__ bd0,
    const float* __restrict__ Wf0, const float* __restrict__ bf0,
    const float* __restrict__ Wd1, const float* __restrict__ bd1,
    const float* __restrict__ Wf1, const float* __restrict__ bf1,
    const float* __restrict__ Wd2, const float* __restrict__ bd2,
    const float* __restrict__ Wf2, const float* __restrict__ bf2,
    const float* __restrict__ Wd3, const float* __restrict__ bd3,
    const float* __restrict__ Wf3, const float* __restrict__ bf3,
    float* __restrict__ out, int N)
{
    __shared__ float es[64 * 127];
    const int tid  = threadIdx.x;
    const int lane = tid & 63;
    const int wave = tid >> 6;
    const int n0   = blockIdx.x * 64;
    const int n    = n0 + lane;
    const bool direct = (blockIdx.y == 0);
    const size_t nctot = (size_t)N * CCH;

    // ---- Phase 0: issue tau-chunk loads early ----
    const int nblk = gridDim.x * 2;
    const int cid  = blockIdx.y * gridDim.x + blockIdx.x;
    const int per  = (int)(nctot / nblk);        // 1344 for N=524288
    const int base_e = cid * per;
    v4f ta[4], tb[4];
#pragma unroll
    for (int it = 0; it < 4; ++it) {
        int off = it * 384 + tid;
        if (off < per) {
            const v4f* t4 = (const v4f*)tau + ((size_t)base_e + off) * 2;
            ta[it] = __builtin_nontemporal_load(t4);
            tb[it] = __builtin_nontemporal_load(t4 + 1);
        }
    }

    // ---- Phase A: MLP -> LDS ----
    float4 c0 = *(const float4*)(cons + (size_t)n * NCON);
    float4 c1 = *(const float4*)(cons + (size_t)n * NCON + 4);
    float x[9] = {c0.x, c0.y, c0.z, c0.w, c1.x, c1.y, c1.z, c1.w, 0.0f};
    if (direct) {
        float mu  = mu_direct[n];
        float inv = __fdividef(1.0f, mu + EPS);
#pragma unroll
        for (int i = 0; i < 8; ++i) x[i] *= inv;
        x[8] = mu;
#pragma unroll 1
        for (int ci = 0; ci < 7; ++ci) {
            int c = __builtin_amdgcn_readfirstlane(wave * 7 + ci);
            float o[3];
            mlp_softmax3<9>(x, c, Wd0, bd0, Wd1, bd1, Wd2, bd2, Wd3, bd3, o);
#pragma unroll
            for (int k = 0; k < 3; ++k) es[lane * 127 + c * 3 + k] = o[k];
        }
    } else {
#pragma unroll 1
        for (int ci = 0; ci < 7; ++ci) {
            int c = __builtin_amdgcn_readfirstlane(wave * 7 + ci);
            float o[3];
            mlp_softmax3<8>(x, c, Wf0, bf0, Wf1, bf1, Wf2, bf2, Wf3, bf3, o);
#pragma unroll
            for (int k = 0; k < 3; ++k) es[lane * 127 + c * 3 + k] = o[k];
        }
    }
    __syncthreads();

    // ---- Phase B: coalesced nt writeout of the 64x126 tile ----
    float* base = out + (direct ? 2 : 5) * nctot + (size_t)n0 * (CCH * 3);
    for (int idx = tid; idx < 64 * 63; idx += 384) {
        int r = idx / 63;
        int q = idx - r * 63;
        v2f v;
        v.x = es[r * 127 + 2 * q];
        v.y = es[r * 127 + 2 * q + 1];
        __builtin_nontemporal_store(v, (v2f*)base + idx);
    }

    // ---- Phase C: consume prefetched tau, write transmissions ----
#pragma unroll
    for (int it = 0; it < 4; ++it) {
        int off = it * 384 + tid;
        if (off < per) {
            int e = base_e + off;
            v4f a = ta[it];
            v4f b = tb[it];
            float s = ((a.x + a.y) + (a.z + a.w)) + ((b.x + b.y) + (b.z + b.w));
            int nn = e / CCH;
            float md = mu_direct[nn] + EPS;
            float mf = mu_diffuse[nn] + EPS;
            __builtin_nontemporal_store(__expf(__fdividef(-s, md)), out + e);
            __builtin_nontemporal_store(__expf(__fdividef(-s, mf)), out + nctot + e);
        }
    }
}

extern "C" void kernel_launch(void* const* d_in, const int* in_sizes, int n_in,
                              void* d_out, int out_size, void* d_ws, size_t ws_size,
                              hipStream_t stream) {
    const float* tau  = (const float*)d_in[0];
    const float* mud  = (const float*)d_in[1];
    const float* muf  = (const float*)d_in[2];
    const float* cons = (const float*)d_in[3];
    // setup_inputs() dict order: Wd{i}, bd{i}, Wf{i}, bf{i} interleaved per layer.
    const float* Wd0 = (const float*)d_in[4];  const float* bd0 = (const float*)d_in[5];
    const float* Wf0 = (const float*)d_in[6];  const float* bf0 = (const float*)d_in[7];
    const float* Wd1 = (const float*)d_in[8];  const float* bd1 = (const float*)d_in[9];
    const float* Wf1 = (const float*)d_in[10]; const float* bf1 = (const float*)d_in[11];
    const float* Wd2 = (const float*)d_in[12]; const float* bd2 = (const float*)d_in[13];
    const float* Wf2 = (const float*)d_in[14]; const float* bf2 = (const float*)d_in[15];
    const float* Wd3 = (const float*)d_in[16]; const float* bd3 = (const float*)d_in[17];
    const float* Wf3 = (const float*)d_in[18]; const float* bf3 = (const float*)d_in[19];
    float* out = (float*)d_out;

    int N = in_sizes[1];            // mu_direct element count = N
    dim3 grid(N / 64, 2);
    k_fused<<<grid, 384, 0, stream>>>(tau, mud, muf, cons,
                                      Wd0, bd0, Wf0, bf0,
                                      Wd1, bd1, Wf1, bf1,
                                      Wd2, bd2, Wf2, bf2,
                                      Wd3, bd3, Wf3, bf3,
                                      out, N);
}

// Round 7
// 294.860 us; speedup vs baseline: 2.9385x; 1.0226x over previous
//
#include <hip/hip_runtime.h>

#define EPS 1e-7f
#define CCH 42
#define NCON 8

typedef float v4f __attribute__((ext_vector_type(4)));
typedef float v2f __attribute__((ext_vector_type(2)));

// ---------------------------------------------------------------------------
// Per-channel MLP (dims NIN -> 5 -> 4 -> 4 -> 3) + 3-way softmax.
// `c` is wave-uniform, so weight/bias loads compile to s_load and FMAs take
// the weight operand from SGPRs.
// ---------------------------------------------------------------------------
template<int NIN>
__device__ __forceinline__ void mlp_softmax3(
    const float x[NIN], int c,
    const float* __restrict__ W0, const float* __restrict__ b0,
    const float* __restrict__ W1, const float* __restrict__ b1,
    const float* __restrict__ W2, const float* __restrict__ b2,
    const float* __restrict__ W3, const float* __restrict__ b3,
    float o[3])
{
    float h0[5];
#pragma unroll
    for (int j = 0; j < 5; ++j) {
        const float* w = W0 + (c * 5 + j) * NIN;
        float a = b0[c * 5 + j];
#pragma unroll
        for (int i = 0; i < NIN; ++i) a = fmaf(x[i], w[i], a);
        h0[j] = fmaxf(a, 0.0f);
    }
    float h1[4];
#pragma unroll
    for (int j = 0; j < 4; ++j) {
        const float* w = W1 + (c * 4 + j) * 5;
        float a = b1[c * 4 + j];
#pragma unroll
        for (int i = 0; i < 5; ++i) a = fmaf(h0[i], w[i], a);
        h1[j] = fmaxf(a, 0.0f);
    }
    float h2[4];
#pragma unroll
    for (int j = 0; j < 4; ++j) {
        const float* w = W2 + (c * 4 + j) * 4;
        float a = b2[c * 4 + j];
#pragma unroll
        for (int i = 0; i < 4; ++i) a = fmaf(h1[i], w[i], a);
        h2[j] = fmaxf(a, 0.0f);
    }
    float lg[3];
#pragma unroll
    for (int j = 0; j < 3; ++j) {
        const float* w = W3 + (c * 3 + j) * 4;
        float a = b3[c * 3 + j];
#pragma unroll
        for (int i = 0; i < 4; ++i) a = fmaf(h2[i], w[i], a);
        lg[j] = a;
    }
    float m = fmaxf(fmaxf(lg[0], lg[1]), lg[2]);
    float e0 = __expf(lg[0] - m);
    float e1 = __expf(lg[1] - m);
    float e2 = __expf(lg[2] - m);
    float r = __fdividef(1.0f, e0 + e1 + e2);
    o[0] = e0 * r;
    o[1] = e1 * r;
    o[2] = e2 * r;
}

// ---------------------------------------------------------------------------
// Fused kernel, software-pipelined. grid = (N/64, 2). Block = 384 thr / 6 waves.
//   Issue order matters (vmcnt is in-order): cons+mu FIRST, then the 8 tau
//   nt-loads. Phase A then waits only vmcnt(8) for cons and the tau stream
//   stays in flight under the whole MLP VALU phase (T4/T14).
//   Phase A: MLP softmax splits (y=0 direct, y=1 diffuse) -> 64x127 LDS tile.
//   Phase B: block-cooperative contiguous nt v2f writeout (full sectors).
//   Phase C: consume prefetched tau regs: sum -> exp -> nt stores.
// ---------------------------------------------------------------------------
__global__ __launch_bounds__(384, 6) void k_fused(
    const float* __restrict__ tau,
    const float* __restrict__ mu_direct,
    const float* __restrict__ mu_diffuse,
    const float* __restrict__ cons,
    const float* __restrict__ Wd0, const float* __restrict__ bd0,
    const float* __restrict__ Wf0, const float* __restrict__ bf0,
    const float* __restrict__ Wd1, const float* __restrict__ bd1,
    const float* __restrict__ Wf1, const float* __restrict__ bf1,
    const float* __restrict__ Wd2, const float* __restrict__ bd2,
    const float* __restrict__ Wf2, const float* __restrict__ bf2,
    const float* __restrict__ Wd3, const float* __restrict__ bd3,
    const float* __restrict__ Wf3, const float* __restrict__ bf3,
    float* __restrict__ out, int N)
{
    __shared__ float es[64 * 127];
    const int tid  = threadIdx.x;
    const int lane = tid & 63;
    const int wave = tid >> 6;
    const int n0   = blockIdx.x * 64;
    const int n    = n0 + lane;
    const bool direct = (blockIdx.y == 0);
    const size_t nctot = (size_t)N * CCH;

    // ---- Issue the phase-A inputs FIRST (oldest in vmcnt order) ----
    float4 c0 = *(const float4*)(cons + (size_t)n * NCON);
    float4 c1 = *(const float4*)(cons + (size_t)n * NCON + 4);
    float mu  = direct ? mu_direct[n] : 0.0f;
    __builtin_amdgcn_sched_barrier(0);   // pin: cons/mu issue before tau loads

    // ---- Then issue the tau-chunk nt loads (younger; stay in flight) ----
    const int nblk = gridDim.x * 2;
    const int cid  = blockIdx.y * gridDim.x + blockIdx.x;
    const int per  = (int)(nctot / nblk);        // 1344 for N=524288
    const int base_e = cid * per;
    v4f ta[4], tb[4];
#pragma unroll
    for (int it = 0; it < 4; ++it) {
        int off = it * 384 + tid;
        if (off < per) {
            const v4f* t4 = (const v4f*)tau + ((size_t)base_e + off) * 2;
            ta[it] = __builtin_nontemporal_load(t4);
            tb[it] = __builtin_nontemporal_load(t4 + 1);
        }
    }
    __builtin_amdgcn_sched_barrier(0);   // pin: tau loads issued before phase A

    // ---- Phase A: MLP -> LDS ----
    float x[9] = {c0.x, c0.y, c0.z, c0.w, c1.x, c1.y, c1.z, c1.w, 0.0f};
    if (direct) {
        float inv = __fdividef(1.0f, mu + EPS);
#pragma unroll
        for (int i = 0; i < 8; ++i) x[i] *= inv;
        x[8] = mu;
#pragma unroll 1
        for (int ci = 0; ci < 7; ++ci) {
            int c = __builtin_amdgcn_readfirstlane(wave * 7 + ci);
            float o[3];
            mlp_softmax3<9>(x, c, Wd0, bd0, Wd1, bd1, Wd2, bd2, Wd3, bd3, o);
#pragma unroll
            for (int k = 0; k < 3; ++k) es[lane * 127 + c * 3 + k] = o[k];
        }
    } else {
#pragma unroll 1
        for (int ci = 0; ci < 7; ++ci) {
            int c = __builtin_amdgcn_readfirstlane(wave * 7 + ci);
            float o[3];
            mlp_softmax3<8>(x, c, Wf0, bf0, Wf1, bf1, Wf2, bf2, Wf3, bf3, o);
#pragma unroll
            for (int k = 0; k < 3; ++k) es[lane * 127 + c * 3 + k] = o[k];
        }
    }
    __syncthreads();

    // ---- Phase B: coalesced nt writeout of the 64x126 tile ----
    float* base = out + (direct ? 2 : 5) * nctot + (size_t)n0 * (CCH * 3);
    for (int idx = tid; idx < 64 * 63; idx += 384) {
        int r = idx / 63;
        int q = idx - r * 63;
        v2f v;
        v.x = es[r * 127 + 2 * q];
        v.y = es[r * 127 + 2 * q + 1];
        __builtin_nontemporal_store(v, (v2f*)base + idx);
    }

    // ---- Phase C: consume prefetched tau, write transmissions ----
#pragma unroll
    for (int it = 0; it < 4; ++it) {
        int off = it * 384 + tid;
        if (off < per) {
            int e = base_e + off;
            v4f a = ta[it];
            v4f b = tb[it];
            float s = ((a.x + a.y) + (a.z + a.w)) + ((b.x + b.y) + (b.z + b.w));
            int nn = e / CCH;
            float md = mu_direct[nn] + EPS;
            float mf = mu_diffuse[nn] + EPS;
            __builtin_nontemporal_store(__expf(__fdividef(-s, md)), out + e);
            __builtin_nontemporal_store(__expf(__fdividef(-s, mf)), out + nctot + e);
        }
    }
}

extern "C" void kernel_launch(void* const* d_in, const int* in_sizes, int n_in,
                              void* d_out, int out_size, void* d_ws, size_t ws_size,
                              hipStream_t stream) {
    const float* tau  = (const float*)d_in[0];
    const float* mud  = (const float*)d_in[1];
    const float* muf  = (const float*)d_in[2];
    const float* cons = (const float*)d_in[3];
    // setup_inputs() dict order: Wd{i}, bd{i}, Wf{i}, bf{i} interleaved per layer.
    const float* Wd0 = (const float*)d_in[4];  const float* bd0 = (const float*)d_in[5];
    const float* Wf0 = (const float*)d_in[6];  const float* bf0 = (const float*)d_in[7];
    const float* Wd1 = (const float*)d_in[8];  const float* bd1 = (const float*)d_in[9];
    const float* Wf1 = (const float*)d_in[10]; const float* bf1 = (const float*)d_in[11];
    const float* Wd2 = (const float*)d_in[12]; const float* bd2 = (const float*)d_in[13];
    const float* Wf2 = (const float*)d_in[14]; const float* bf2 = (const float*)d_in[15];
    const float* Wd3 = (const float*)d_in[16]; const float* bd3 = (const float*)d_in[17];
    const float* Wf3 = (const float*)d_in[18]; const float* bf3 = (const float*)d_in[19];
    float* out = (float*)d_out;

    int N = in_sizes[1];            // mu_direct element count = N
    dim3 grid(N / 64, 2);
    k_fused<<<grid, 384, 0, stream>>>(tau, mud, muf, cons,
                                      Wd0, bd0, Wf0, bf0,
                                      Wd1, bd1, Wf1, bf1,
                                      Wd2, bd2, Wf2, bf2,
                                      Wd3, bd3, Wf3, bf3,
                                      out, N);
}